// Round 3
// baseline (1120.456 us; speedup 1.0000x reference)
//
#include <hip/hip_runtime.h>

#define NVAR 100000
#define NCON 50000
#define DVAR 8
#define DCON 16
#define DIN 32
#define DH 128
#define DCAT 288

__device__ __forceinline__ float f4c(const float4& v, int kk) {
    switch (kk) { case 0: return v.x; case 1: return v.y; case 2: return v.z; default: return v.w; }
}

// ---------------------------------------------------------------- init: h = x @ W + b
__global__ __launch_bounds__(256) void init_kernel(
    const float* __restrict__ x,
    const float* __restrict__ Wv, const float* __restrict__ bv,
    const float* __restrict__ Wc, const float* __restrict__ bc,
    float* __restrict__ v, float* __restrict__ c)
{
    const int t = threadIdx.x;
    const int n = t & 127;
    const int rsub = t >> 7;                 // 0..1
    const int rbase = blockIdx.x * 8;
    #pragma unroll
    for (int rr = 0; rr < 4; ++rr) {
        int row = rbase + rr * 2 + rsub;
        if (row >= NVAR + NCON) return;
        const float* W; const float* b; float* o; int orow;
        if (row < NVAR) { W = Wv; b = bv; o = v; orow = row; }
        else            { W = Wc; b = bc; o = c; orow = row - NVAR; }
        float acc = b[n];
        const float* xr = x + (size_t)row * DIN;
        #pragma unroll
        for (int k = 0; k < DIN; ++k) acc += xr[k] * W[k * DH + n];
        o[(size_t)orow * DH + n] = acc;
    }
}

// ---------------------------------------------------------------- gather-sum:
// agg[row] = sum_d h_nb[idx[row][d]]   (16 threads/row, 8 floats each, all loads independent)
template<int DEG>
__global__ __launch_bounds__(256) void agg_kernel(
    const float* __restrict__ h_nb, const int* __restrict__ idx,
    float* __restrict__ agg, int M)
{
    const int tid = blockIdx.x * 256 + threadIdx.x;
    const int row = tid >> 4;
    const int part = tid & 15;               // 8-float slice
    if (row >= M) return;
    int nb[DEG];
    #pragma unroll
    for (int d4 = 0; d4 < DEG / 4; ++d4)
        *reinterpret_cast<int4*>(&nb[d4 * 4]) =
            *reinterpret_cast<const int4*>(idx + (size_t)row * DEG + d4 * 4);
    float4 a0 = make_float4(0.f, 0.f, 0.f, 0.f);
    float4 a1 = make_float4(0.f, 0.f, 0.f, 0.f);
    #pragma unroll
    for (int d = 0; d < DEG; ++d) {
        const float* p = h_nb + (size_t)nb[d] * DH + part * 8;
        const float4 v0 = *reinterpret_cast<const float4*>(p);
        const float4 v1 = *reinterpret_cast<const float4*>(p + 4);
        a0.x += v0.x; a0.y += v0.y; a0.z += v0.z; a0.w += v0.w;
        a1.x += v1.x; a1.y += v1.y; a1.z += v1.z; a1.w += v1.w;
    }
    float* o = agg + (size_t)row * DH + part * 8;
    *reinterpret_cast<float4*>(o) = a0;
    *reinterpret_cast<float4*>(o + 4) = a1;
}

// ---------------------------------------------------------------- GEMM:
// h_out = [agg | h_self | x_self] @ W + b ; 64 rows/block, no LDS, no barriers
__global__ __launch_bounds__(256) void gemm_kernel(
    const float* __restrict__ agg,
    const float* __restrict__ h_self,
    const float* __restrict__ x_self,
    const float* __restrict__ W,     // DCAT x DH
    const float* __restrict__ b,
    float* __restrict__ h_out,
    int M)
{
    const int t = threadIdx.x;
    const int tn = t & 15;
    const int tm = t >> 4;           // 0..15
    const int rm = tm * 4;
    const int cn = tn * 4;           // cols cn..cn+3 and cn+64..cn+67
    const int row0 = blockIdx.x * 64 + rm;
    int rc[4];
    #pragma unroll
    for (int i = 0; i < 4; ++i) { int r = row0 + i; rc[i] = r < M ? r : M - 1; }

    float acc[4][8];
    #pragma unroll
    for (int i = 0; i < 4; ++i)
        #pragma unroll
        for (int j = 0; j < 8; ++j) acc[i][j] = 0.f;

    // Segment 1: k in [0,128) from agg
    #pragma unroll 2
    for (int k = 0; k < DH; k += 4) {
        float4 a4[4];
        #pragma unroll
        for (int i = 0; i < 4; ++i)
            a4[i] = *reinterpret_cast<const float4*>(agg + (size_t)rc[i] * DH + k);
        #pragma unroll
        for (int kk = 0; kk < 4; ++kk) {
            float4 w0 = *reinterpret_cast<const float4*>(W + (size_t)(k + kk) * DH + cn);
            float4 w1 = *reinterpret_cast<const float4*>(W + (size_t)(k + kk) * DH + cn + 64);
            #pragma unroll
            for (int i = 0; i < 4; ++i) {
                float a = f4c(a4[i], kk);
                acc[i][0] += a * w0.x; acc[i][1] += a * w0.y;
                acc[i][2] += a * w0.z; acc[i][3] += a * w0.w;
                acc[i][4] += a * w1.x; acc[i][5] += a * w1.y;
                acc[i][6] += a * w1.z; acc[i][7] += a * w1.w;
            }
        }
    }
    // Segment 2: k in [128,256) from h_self
    #pragma unroll 2
    for (int k = 0; k < DH; k += 4) {
        float4 a4[4];
        #pragma unroll
        for (int i = 0; i < 4; ++i)
            a4[i] = *reinterpret_cast<const float4*>(h_self + (size_t)rc[i] * DH + k);
        #pragma unroll
        for (int kk = 0; kk < 4; ++kk) {
            float4 w0 = *reinterpret_cast<const float4*>(W + (size_t)(DH + k + kk) * DH + cn);
            float4 w1 = *reinterpret_cast<const float4*>(W + (size_t)(DH + k + kk) * DH + cn + 64);
            #pragma unroll
            for (int i = 0; i < 4; ++i) {
                float a = f4c(a4[i], kk);
                acc[i][0] += a * w0.x; acc[i][1] += a * w0.y;
                acc[i][2] += a * w0.z; acc[i][3] += a * w0.w;
                acc[i][4] += a * w1.x; acc[i][5] += a * w1.y;
                acc[i][6] += a * w1.z; acc[i][7] += a * w1.w;
            }
        }
    }
    // Segment 3: k in [256,288) from x_self
    #pragma unroll 2
    for (int k = 0; k < DIN; k += 4) {
        float4 a4[4];
        #pragma unroll
        for (int i = 0; i < 4; ++i)
            a4[i] = *reinterpret_cast<const float4*>(x_self + (size_t)rc[i] * DIN + k);
        #pragma unroll
        for (int kk = 0; kk < 4; ++kk) {
            float4 w0 = *reinterpret_cast<const float4*>(W + (size_t)(2 * DH + k + kk) * DH + cn);
            float4 w1 = *reinterpret_cast<const float4*>(W + (size_t)(2 * DH + k + kk) * DH + cn + 64);
            #pragma unroll
            for (int i = 0; i < 4; ++i) {
                float a = f4c(a4[i], kk);
                acc[i][0] += a * w0.x; acc[i][1] += a * w0.y;
                acc[i][2] += a * w0.z; acc[i][3] += a * w0.w;
                acc[i][4] += a * w1.x; acc[i][5] += a * w1.y;
                acc[i][6] += a * w1.z; acc[i][7] += a * w1.w;
            }
        }
    }

    #pragma unroll
    for (int i = 0; i < 4; ++i) {
        int row = row0 + i;
        if (row < M) {
            float4 o0, o1;
            o0.x = acc[i][0] + b[cn + 0]; o0.y = acc[i][1] + b[cn + 1];
            o0.z = acc[i][2] + b[cn + 2]; o0.w = acc[i][3] + b[cn + 3];
            o1.x = acc[i][4] + b[cn + 64]; o1.y = acc[i][5] + b[cn + 65];
            o1.z = acc[i][6] + b[cn + 66]; o1.w = acc[i][7] + b[cn + 67];
            *reinterpret_cast<float4*>(h_out + (size_t)row * DH + cn) = o0;
            *reinterpret_cast<float4*>(h_out + (size_t)row * DH + cn + 64) = o1;
        }
    }
}

// ---------------------------------------------------------------- column-sum partials of v
__global__ __launch_bounds__(256) void reduce_kernel(
    const float* __restrict__ v, float* __restrict__ part)
{
    __shared__ float sred[256];
    const int t = threadIdx.x;
    const int col = t & 127;
    const int half = t >> 7;
    float local = 0.f;
    for (int r = blockIdx.x * 2 + half; r < NVAR; r += 256)
        local += v[(size_t)r * DH + col];
    sred[t] = local;
    __syncthreads();
    if (t < 128) part[blockIdx.x * DH + t] = sred[t] + sred[t + 128];
}

// ---------------------------------------------------------------- s = g . Wq[0:128] + bq
__global__ __launch_bounds__(256) void finalize_kernel(
    const float* __restrict__ part, const float* __restrict__ Wq,
    const float* __restrict__ bq, float* __restrict__ sout)
{
    __shared__ float sred[256];
    const int t = threadIdx.x;
    const int col = t & 127;
    const int half = t >> 7;
    float gp = 0.f;
    #pragma unroll 4
    for (int bb = half; bb < 128; bb += 2) gp += part[(size_t)bb * DH + col];
    sred[t] = gp * Wq[col];
    __syncthreads();
    if (t < 128) sred[t] += sred[t + 128];
    __syncthreads();
    if (t < 64) {
        float val = sred[t] + sred[t + 64];
        #pragma unroll
        for (int off = 32; off > 0; off >>= 1) val += __shfl_down(val, off);
        if (t == 0) sout[0] = val + bq[0];
    }
}

// ---------------------------------------------------------------- out[i] = s + v[i] . Wq[128:256]
__global__ __launch_bounds__(256) void out_kernel(
    const float* __restrict__ v, const float* __restrict__ Wq,
    const float* __restrict__ sIn, float* __restrict__ outp)
{
    const int lane = threadIdx.x & 63;
    const int wave = blockIdx.x * 4 + (threadIdx.x >> 6);
    const float wq0 = Wq[DH + lane];
    const float wq1 = Wq[DH + 64 + lane];
    const float s = sIn[0];
    const int rbase = wave * 64;
    #pragma unroll 4
    for (int rr = 0; rr < 64; ++rr) {
        int r = rbase + rr;
        if (r >= NVAR) continue;
        float val = v[(size_t)r * DH + lane] * wq0 + v[(size_t)r * DH + 64 + lane] * wq1;
        #pragma unroll
        for (int off = 32; off > 0; off >>= 1) val += __shfl_down(val, off);
        if (lane == 0) outp[r] = s + val;
    }
}

extern "C" void kernel_launch(void* const* d_in, const int* in_sizes, int n_in,
                              void* d_out, int out_size, void* d_ws, size_t ws_size,
                              hipStream_t stream)
{
    const float* x    = (const float*)d_in[0];
    const int*   vci  = (const int*)  d_in[1];   // NVAR x 8, values < NCON
    const int*   cvi  = (const int*)  d_in[2];   // NCON x 16, values < NVAR
    const float* Wiv  = (const float*)d_in[3];
    const float* biv  = (const float*)d_in[4];
    const float* Wic  = (const float*)d_in[5];
    const float* bic  = (const float*)d_in[6];
    const float* Wvar = (const float*)d_in[7];
    const float* bvar = (const float*)d_in[8];
    const float* Wcon = (const float*)d_in[9];
    const float* bcon = (const float*)d_in[10];
    const float* Wq   = (const float*)d_in[11];
    const float* bq   = (const float*)d_in[12];
    float* outp = (float*)d_out;

    float* ws = (float*)d_ws;
    size_t off = 0;
    float* vA  = ws + off; off += (size_t)NVAR * DH;
    float* vB  = ws + off; off += (size_t)NVAR * DH;
    float* cA  = ws + off; off += (size_t)NCON * DH;
    float* cB  = ws + off; off += (size_t)NCON * DH;
    float* agg = ws + off; off += (size_t)NVAR * DH;   // shared agg scratch (max size)
    float* part = ws + off; off += 128 * DH;
    float* sbuf = ws + off; off += 1;

    const float* xc = x + (size_t)NVAR * DIN;

    // init: v0, c0
    init_kernel<<<(NVAR + NCON) / 8, 256, 0, stream>>>(x, Wiv, biv, Wic, bic, vA, cA);

    // layer 1: c1 = f(agg(v0), c0, xc)
    agg_kernel<DCON><<<(NCON * 16 + 255) / 256, 256, 0, stream>>>(vA, cvi, agg, NCON);
    gemm_kernel<<<(NCON + 63) / 64, 256, 0, stream>>>(agg, cA, xc, Wcon, bcon, cB, NCON);
    //          v1 = f(agg(c0), v0, xv)
    agg_kernel<DVAR><<<(NVAR * 16 + 255) / 256, 256, 0, stream>>>(cA, vci, agg, NVAR);
    gemm_kernel<<<(NVAR + 63) / 64, 256, 0, stream>>>(agg, vA, x, Wvar, bvar, vB, NVAR);

    // layer 2: only v2 needed (c2 dead)
    agg_kernel<DVAR><<<(NVAR * 16 + 255) / 256, 256, 0, stream>>>(cB, vci, agg, NVAR);
    gemm_kernel<<<(NVAR + 63) / 64, 256, 0, stream>>>(agg, vB, x, Wvar, bvar, vA, NVAR);

    // readout
    reduce_kernel<<<128, 256, 0, stream>>>(vA, part);
    finalize_kernel<<<1, 256, 0, stream>>>(part, Wq, bq, sbuf);
    out_kernel<<<(NVAR + 255) / 256, 256, 0, stream>>>(vA, Wq, sbuf, outp);
}

// Round 4
// 285.265 us; speedup vs baseline: 3.9278x; 3.9278x over previous
//
#include <hip/hip_runtime.h>

#define NV 100000
#define NC 50000
#define DVAR 8
#define DCON 16

using short8 = __attribute__((ext_vector_type(8))) short;
using f32x4  = __attribute__((ext_vector_type(4))) float;

__device__ __forceinline__ unsigned short f2bf(float f) {
    union { float f; unsigned int u; } v; v.f = f;
    return (unsigned short)((v.u + 0x7fffu + ((v.u >> 16) & 1u)) >> 16);  // RNE
}
__device__ __forceinline__ float bflo(unsigned int u) {
    union { unsigned int u; float f; } v; v.u = u << 16; return v.f;
}
__device__ __forceinline__ float bfhi(unsigned int u) {
    union { unsigned int u; float f; } v; v.u = u & 0xffff0000u; return v.f;
}

// ---------------------------------------------------------------- pack W into MFMA B-fragment
// layout: elem[(s*128 + c)*32 + k'] = bf16(W[(s*32 + k')*128 + c]); lane reads 16B at k'=(lane>>4)*8
__global__ __launch_bounds__(256) void pack_kernel(
    const float* __restrict__ Wvar, const float* __restrict__ Wcon,
    const float* __restrict__ Wiv,  const float* __restrict__ Wic,
    unsigned short* __restrict__ WbVar, unsigned short* __restrict__ WbCon,
    unsigned short* __restrict__ WbIv,  unsigned short* __restrict__ WbIc,
    float* __restrict__ S)
{
    const int tid = blockIdx.x * 256 + threadIdx.x;
    for (int i = tid; i < 9 * 128 * 32; i += gridDim.x * 256) {
        int s = i >> 12, rem = i & 4095, c = rem >> 5, k = rem & 31;
        int src = (s * 32 + k) * 128 + c;
        WbVar[i] = f2bf(Wvar[src]);
        WbCon[i] = f2bf(Wcon[src]);
    }
    for (int i = tid; i < 128 * 32; i += gridDim.x * 256) {
        int c = i >> 5, k = i & 31;
        int src = k * 128 + c;
        WbIv[i] = f2bf(Wiv[src]);
        WbIc[i] = f2bf(Wic[src]);
    }
    if (tid == 0) S[0] = 0.f;
}

// ---------------------------------------------------------------- init: h = bf16(x) @ W + b  (K=32, 1 step)
__global__ __launch_bounds__(256) void init_mfma(
    const float* __restrict__ x,          // M x 32 (pre-offset)
    const unsigned short* __restrict__ Wb,
    const float* __restrict__ bias,
    unsigned short* __restrict__ hout, int M)
{
    const int t = threadIdx.x;
    const int lane = t & 63;
    const int w = t >> 6;
    const int lrow = lane & 15;
    const int lg = lane >> 4;
    const int wrow0 = blockIdx.x * 64 + w * 16;
    int arow = wrow0 + lrow;
    int arowc = arow < M ? arow : M - 1;

    const float4* xp = (const float4*)(x + (size_t)arowc * 32 + lg * 8);
    float4 xa = xp[0], xb = xp[1];
    short8 afr;
    afr[0] = (short)f2bf(xa.x); afr[1] = (short)f2bf(xa.y);
    afr[2] = (short)f2bf(xa.z); afr[3] = (short)f2bf(xa.w);
    afr[4] = (short)f2bf(xb.x); afr[5] = (short)f2bf(xb.y);
    afr[6] = (short)f2bf(xb.z); afr[7] = (short)f2bf(xb.w);

    #pragma unroll
    for (int ct = 0; ct < 8; ++ct) {
        int c = ct * 16 + lrow;
        short8 bfr = *(const short8*)(Wb + (size_t)c * 32 + lg * 8);
        f32x4 acc = {0.f, 0.f, 0.f, 0.f};
        acc = __builtin_amdgcn_mfma_f32_16x16x32_bf16(afr, bfr, acc, 0, 0, 0);
        float bv = bias[c];
        #pragma unroll
        for (int r = 0; r < 4; ++r) {
            int orow = wrow0 + lg * 4 + r;
            if (orow < M) hout[(size_t)orow * 128 + c] = f2bf(acc[r] + bv);
        }
    }
}

// ---------------------------------------------------------------- fused layer:
// h_out = [agg(h_nb[idx]) | h_self | x_self] @ W + b   (K = 288 = 9 MFMA steps)
// FINAL: instead of storing h, emit dot1[row] = h[row]·Wq[128:] and atomicAdd S += Σ h[row]·Wq[:128]
template<int DEG, bool FINAL>
__global__ __launch_bounds__(256) void layer_mfma(
    const unsigned short* hself,      // no restrict: may alias hout (in-place v-update)
    const unsigned short* __restrict__ hnb,
    const float* __restrict__ xself,
    const int* __restrict__ idx,
    const unsigned short* __restrict__ Wb,
    const float* __restrict__ bias,
    unsigned short* hout,
    const float* __restrict__ Wq, float* __restrict__ S, float* __restrict__ dotout,
    int M)
{
    __shared__ unsigned short A[64 * 136];   // agg cols 0..127, row stride 136 (conflict-free b128)
    __shared__ float red[4];
    const int t = threadIdx.x;
    const int r0 = blockIdx.x * 64;

    // ---- phase 1: gather-sum (bf16 in, fp32 accum, bf16 to LDS)
    {
        const int part = t & 15;             // 8-elem slice
        const int gr = t >> 4;               // 0..15
        #pragma unroll
        for (int rr = gr; rr < 64; rr += 16) {
            int row = r0 + rr;
            int rowc = row < M ? row : M - 1;
            int nb[DEG];
            #pragma unroll
            for (int d4 = 0; d4 < DEG / 4; ++d4)
                *(int4*)(&nb[d4 * 4]) = *(const int4*)(idx + (size_t)rowc * DEG + d4 * 4);
            float a0=0.f,a1=0.f,a2=0.f,a3=0.f,a4=0.f,a5=0.f,a6=0.f,a7=0.f;
            #pragma unroll
            for (int d = 0; d < DEG; ++d) {
                const uint4 q = *(const uint4*)(hnb + (size_t)nb[d] * 128 + part * 8);
                a0 += bflo(q.x); a1 += bfhi(q.x);
                a2 += bflo(q.y); a3 += bfhi(q.y);
                a4 += bflo(q.z); a5 += bfhi(q.z);
                a6 += bflo(q.w); a7 += bfhi(q.w);
            }
            uint4 o;
            o.x = (unsigned)f2bf(a0) | ((unsigned)f2bf(a1) << 16);
            o.y = (unsigned)f2bf(a2) | ((unsigned)f2bf(a3) << 16);
            o.z = (unsigned)f2bf(a4) | ((unsigned)f2bf(a5) << 16);
            o.w = (unsigned)f2bf(a6) | ((unsigned)f2bf(a7) << 16);
            *(uint4*)(&A[rr * 136 + part * 8]) = o;
        }
    }
    __syncthreads();

    // ---- phase 2: MFMA over K=288
    const int lane = t & 63;
    const int w = t >> 6;
    const int lrow = lane & 15;
    const int lg = lane >> 4;
    const int wrow0 = r0 + w * 16;
    int arow = wrow0 + lrow;
    int arowc = arow < M ? arow : M - 1;

    f32x4 acc[8];
    #pragma unroll
    for (int ct = 0; ct < 8; ++ct) acc[ct] = (f32x4){0.f, 0.f, 0.f, 0.f};

    #pragma unroll
    for (int s = 0; s < 9; ++s) {
        short8 afr;
        if (s < 4) {
            afr = *(const short8*)(&A[(w * 16 + lrow) * 136 + s * 32 + lg * 8]);
        } else if (s < 8) {
            afr = *(const short8*)(hself + (size_t)arowc * 128 + (s - 4) * 32 + lg * 8);
        } else {
            const float4* xp = (const float4*)(xself + (size_t)arowc * 32 + lg * 8);
            float4 xa = xp[0], xb = xp[1];
            afr[0] = (short)f2bf(xa.x); afr[1] = (short)f2bf(xa.y);
            afr[2] = (short)f2bf(xa.z); afr[3] = (short)f2bf(xa.w);
            afr[4] = (short)f2bf(xb.x); afr[5] = (short)f2bf(xb.y);
            afr[6] = (short)f2bf(xb.z); afr[7] = (short)f2bf(xb.w);
        }
        #pragma unroll
        for (int ct = 0; ct < 8; ++ct) {
            short8 bfr = *(const short8*)(Wb + ((size_t)s * 128 + ct * 16 + lrow) * 32 + lg * 8);
            acc[ct] = __builtin_amdgcn_mfma_f32_16x16x32_bf16(afr, bfr, acc[ct], 0, 0, 0);
        }
    }

    // ---- epilogue (C layout: col = lane&15, row = (lane>>4)*4 + reg)
    if (!FINAL) {
        #pragma unroll
        for (int ct = 0; ct < 8; ++ct) {
            int c = ct * 16 + lrow;
            float bv = bias[c];
            #pragma unroll
            for (int r = 0; r < 4; ++r) {
                int orow = wrow0 + lg * 4 + r;
                if (orow < M) hout[(size_t)orow * 128 + c] = f2bf(acc[ct][r] + bv);
            }
        }
    } else {
        float d0[4] = {0.f, 0.f, 0.f, 0.f};   // · Wq[0:128]  (for global g·Wq scalar)
        float d1[4] = {0.f, 0.f, 0.f, 0.f};   // · Wq[128:256] (per-row)
        #pragma unroll
        for (int ct = 0; ct < 8; ++ct) {
            int c = ct * 16 + lrow;
            float bv = bias[c];
            float wq0 = Wq[c];
            float wq1 = Wq[128 + c];
            #pragma unroll
            for (int r = 0; r < 4; ++r) {
                int orow = wrow0 + lg * 4 + r;
                float val = (orow < M) ? (acc[ct][r] + bv) : 0.f;
                d0[r] += val * wq0;
                d1[r] += val * wq1;
            }
        }
        // butterfly over col bits (lanes 0-3 of lrow): every lane gets its row-group's full dot
        #pragma unroll
        for (int r = 0; r < 4; ++r) {
            d0[r] += __shfl_xor(d0[r], 1); d0[r] += __shfl_xor(d0[r], 2);
            d0[r] += __shfl_xor(d0[r], 4); d0[r] += __shfl_xor(d0[r], 8);
            d1[r] += __shfl_xor(d1[r], 1); d1[r] += __shfl_xor(d1[r], 2);
            d1[r] += __shfl_xor(d1[r], 4); d1[r] += __shfl_xor(d1[r], 8);
        }
        if (lrow == 0) {
            #pragma unroll
            for (int r = 0; r < 4; ++r) {
                int orow = wrow0 + lg * 4 + r;
                if (orow < M) dotout[orow] = d1[r];
            }
        }
        // wave total of d0 → block total → one atomicAdd per block
        float tot = d0[0] + d0[1] + d0[2] + d0[3];
        tot += __shfl_xor(tot, 16);
        tot += __shfl_xor(tot, 32);
        if (lane == 0) red[w] = tot;
        __syncthreads();
        if (t == 0) atomicAdd(S, red[0] + red[1] + red[2] + red[3]);
    }
}

// ---------------------------------------------------------------- out[i] = dot1[i] + S + bq
__global__ __launch_bounds__(256) void addout_kernel(
    float* __restrict__ outp, const float* __restrict__ S,
    const float* __restrict__ bq, int n)
{
    int i = blockIdx.x * 256 + threadIdx.x;
    if (i < n) outp[i] = outp[i] + S[0] + bq[0];
}

extern "C" void kernel_launch(void* const* d_in, const int* in_sizes, int n_in,
                              void* d_out, int out_size, void* d_ws, size_t ws_size,
                              hipStream_t stream)
{
    const float* x    = (const float*)d_in[0];
    const int*   vci  = (const int*)  d_in[1];   // NV x 8,  values < NC
    const int*   cvi  = (const int*)  d_in[2];   // NC x 16, values < NV
    const float* Wiv  = (const float*)d_in[3];
    const float* biv  = (const float*)d_in[4];
    const float* Wic  = (const float*)d_in[5];
    const float* bic  = (const float*)d_in[6];
    const float* Wvar = (const float*)d_in[7];
    const float* bvar = (const float*)d_in[8];
    const float* Wcon = (const float*)d_in[9];
    const float* bcon = (const float*)d_in[10];
    const float* Wq   = (const float*)d_in[11];
    const float* bq   = (const float*)d_in[12];
    float* outp = (float*)d_out;

    unsigned short* us = (unsigned short*)d_ws;
    size_t o = 0;
    unsigned short* vA    = us + o; o += (size_t)NV * 128;   // v0, then v1 in-place
    unsigned short* cA    = us + o; o += (size_t)NC * 128;   // c0
    unsigned short* cB    = us + o; o += (size_t)NC * 128;   // c1
    unsigned short* WbVar = us + o; o += 9 * 128 * 32;
    unsigned short* WbCon = us + o; o += 9 * 128 * 32;
    unsigned short* WbIv  = us + o; o += 128 * 32;
    unsigned short* WbIc  = us + o; o += 128 * 32;
    float* S = (float*)(us + o);                              // o is even → 4B aligned

    const float* xc = x + (size_t)NV * 32;

    // weight pack + S zero
    pack_kernel<<<144, 256, 0, stream>>>(Wvar, Wcon, Wiv, Wic, WbVar, WbCon, WbIv, WbIc, S);
    // init
    init_mfma<<<(NV + 63) / 64, 256, 0, stream>>>(x,  WbIv, biv, vA, NV);
    init_mfma<<<(NC + 63) / 64, 256, 0, stream>>>(xc, WbIc, bic, cA, NC);
    // layer 1: c1 = f(agg(v0), c0, xc)  [must run before v-update overwrites nothing: reads vA=v0]
    layer_mfma<DCON, false><<<(NC + 63) / 64, 256, 0, stream>>>(
        cA, vA, xc, cvi, WbCon, bcon, cB, nullptr, nullptr, nullptr, NC);
    //          v1 = f(agg(c0), v0, xv)  [in-place: blocks only read their own v rows]
    layer_mfma<DVAR, false><<<(NV + 63) / 64, 256, 0, stream>>>(
        vA, cA, x, vci, WbVar, bvar, vA, nullptr, nullptr, nullptr, NV);
    // layer 2: v2 = f(agg(c1), v1, xv) fused with readout (c2 dead)
    layer_mfma<DVAR, true><<<(NV + 63) / 64, 256, 0, stream>>>(
        vA, cB, x, vci, WbVar, bvar, nullptr, Wq, S, outp, NV);
    // out[i] = dot1[i] + (g·Wq[:128]) + bq
    addout_kernel<<<(NV + 255) / 256, 256, 0, stream>>>(outp, S, bq, NV);
}